// Round 15
// baseline (50.605 us; speedup 1.0000x reference)
//
#include <hip/hip_runtime.h>
#include <math.h>

#define B_ 1000
#define D_ 8
#define PRE_ 98
#define NXT_ 2048
#define J_ 32
#define K_ 64
#define A_ 5

typedef __attribute__((ext_vector_type(8))) __bf16 bf16x8;
typedef __attribute__((ext_vector_type(4))) float f32x4;
typedef __attribute__((ext_vector_type(16))) float f32x16;
typedef __attribute__((ext_vector_type(8))) unsigned short us8;

__device__ __forceinline__ unsigned cvtpk(float lo, float hi) {
  unsigned r;
  asm("v_cvt_pk_bf16_f32 %0, %1, %2" : "=v"(r) : "v"(lo), "v"(hi));
  return r;
}

__device__ __forceinline__ void gload16(const void* g, void* l) {
  __builtin_amdgcn_global_load_lds(
      (const __attribute__((address_space(1))) void*)g,
      (__attribute__((address_space(3))) void*)l, 16, 0, 0);
}

union bfu { unsigned u[4]; bf16x8 v; };

// ws layout (float offsets): R13 layout (unchanged)
//   [0, 1048576)        S1part[oc4][1024 b][8 d][32 j] f32 (4 MB)
//   [1048576, 1966080)  w1a fragments   [1966080, 2424832) xa fragments
//   [2424832, 2686976)  wca fragments
//   [2686976, +4096) spsum  [2691072, +4096) spsq  [2695168, +2048) wcp
//   [2697216, +256) hvec[d*32+j]   [2697472, +32) nz[j]

// 833 blocks: [0,512) W1, [512,768) x, [768,832) Wc(+wcsum), 832 = hvec/nz
__global__ __launch_bounds__(256) void kcvt(
    const float* __restrict__ x, const float* __restrict__ W1,
    const float* __restrict__ b1, const float* __restrict__ Wc,
    const float* __restrict__ h_mat, const float* __restrict__ a_mat,
    const float* __restrict__ noise, const float* __restrict__ indicator,
    unsigned short* __restrict__ w1a, unsigned short* __restrict__ xa,
    unsigned short* __restrict__ wca, float* __restrict__ wcp,
    float* __restrict__ hvec, float* __restrict__ nz) {
  __shared__ float sbuf[32 * 257];
  __shared__ float extra[32];
  __shared__ float ws2[32][9];

  const int bid = blockIdx.x, tid = threadIdx.x;

  if (bid < 512) {  // ---- W1: tile (d, og) = 32 rows x 98 k, contiguous ----
    const int d = bid & 7, og = bid >> 3;
    const float* base = W1 + (size_t)3136 * (d * 64 + og);  // 16B-aligned
    for (int idx = tid; idx < 784; idx += 256) {
      float4 v4 = ((const float4*)base)[idx];
      int p = idx * 4;
      const float vv[4] = {v4.x, v4.y, v4.z, v4.w};
#pragma unroll
      for (int e = 0; e < 4; ++e) {
        int pp = p + e;
        int r = pp / 98, k = pp - r * 98;
        sbuf[r * 99 + k] = vv[e];
      }
    }
    if (tid < 32) extra[tid] = b1[d * NXT_ + og * 32 + tid];
    __syncthreads();
    unsigned short* dst = w1a + (size_t)((d * 64 + og) * 7) * 512;
#pragma unroll
    for (int q = 0; q < 2; ++q) {
      int s = tid + q * 256;
      if (s < 448) {
        int ks = s >> 6, l = s & 63;
        int r = l & 31, k0 = ks * 16 + (l >> 5) * 8;
        const float* row = sbuf + r * 99;
        bfu v;
#pragma unroll
        for (int p = 0; p < 4; ++p) {
          int k = k0 + 2 * p;
          float f0 = (k < 98) ? row[k] : ((k == 98) ? extra[r] : 0.0f);
          float f1 = (k + 1 < 98) ? row[k + 1] : ((k + 1 == 98) ? extra[r] : 0.0f);
          v.u[p] = cvtpk(f0, f1);
        }
        *(bf16x8*)(dst + (size_t)s * 8) = v.v;
      }
    }
  } else if (bid < 768) {  // ---- x: tile (d, bg) = 32 rows x 98 k ----
    const int b2 = bid - 512;
    const int d = b2 & 7, bg = b2 >> 3;
    for (int idx = tid; idx < 1568; idx += 256) {  // 32 rows x 49 float2
      int r = idx / 49, c = idx - r * 49;
      int gb = bg * 32 + r;
      float2 v2 = make_float2(0.0f, 0.0f);
      if (gb < B_)
        v2 = *(const float2*)(x + (size_t)gb * (D_ * PRE_) + d * PRE_ + 2 * c);
      sbuf[r * 99 + 2 * c] = v2.x;
      sbuf[r * 99 + 2 * c + 1] = v2.y;
    }
    __syncthreads();
    unsigned short* dst = xa + (size_t)((d * 32 + bg) * 7) * 512;
#pragma unroll
    for (int q = 0; q < 2; ++q) {
      int s = tid + q * 256;
      if (s < 448) {
        int ks = s >> 6, l = s & 63;
        int r = l & 31, k0 = ks * 16 + (l >> 5) * 8;
        bool valid = (bg * 32 + r) < B_;
        const float* row = sbuf + r * 99;
        bfu v;
#pragma unroll
        for (int p = 0; p < 4; ++p) {
          int k = k0 + 2 * p;
          float f0 = 0.0f, f1 = 0.0f;
          if (valid) {
            f0 = (k < 98) ? row[k] : ((k == 98) ? 1.0f : 0.0f);
            f1 = (k + 1 < 98) ? row[k + 1] : ((k + 1 == 98) ? 1.0f : 0.0f);
          }
          v.u[p] = cvtpk(f0, f1);
        }
        *(bf16x8*)(dst + (size_t)s * 8) = v.v;
      }
    }
  } else if (bid < 832) {  // ---- Wc: tile (d, oq) = 32 j-rows x 256 o ----
    const int b3 = bid - 768;
    const int d = b3 & 7, oq = b3 >> 3;
    for (int idx = tid; idx < 2048; idx += 256) {  // 32 rows x 64 float4
      int j = idx >> 6, c = idx & 63;
      float4 v4 = *(const float4*)(Wc + ((size_t)d * J_ + j) * NXT_ +
                                   oq * 256 + 4 * c);
      float* p = sbuf + j * 257 + 4 * c;
      p[0] = v4.x;
      p[1] = v4.y;
      p[2] = v4.z;
      p[3] = v4.w;
    }
    __syncthreads();
    unsigned short* dst = wca + (size_t)((d * 64 + oq * 8) * 2) * 512;
#pragma unroll
    for (int q = 0; q < 4; ++q) {
      int s = tid + q * 256;
      int ogl = s >> 7, t2 = (s >> 6) & 1, l = s & 63;
      int j = l & 31;
      int ol = ogl * 32 + t2 * 16 + (l >> 5) * 8;
      const float* row = sbuf + j * 257 + ol;
      bfu v;
#pragma unroll
      for (int p = 0; p < 4; ++p) v.u[p] = cvtpk(row[2 * p], row[2 * p + 1]);
      *(bf16x8*)(dst + (size_t)s * 8) = v.v;
    }
    {
      int j = tid >> 3, seg = tid & 7;
      const float* row = sbuf + j * 257 + seg * 32;
      float sacc = 0.0f;
#pragma unroll
      for (int i = 0; i < 32; ++i) sacc += row[i];
      ws2[j][seg] = sacc;
    }
    __syncthreads();
    if (tid < 32) {
      float t = 0.0f;
#pragma unroll
      for (int g = 0; g < 8; ++g) t += ws2[tid][g];
      wcp[((size_t)d * 32 + tid) * 8 + oq] = t;
    }
  } else {  // ---- hvec/nz ----
    int dd = tid >> 5, j = tid & 31;
    float hs[A_] = {0, 0, 0, 0, 0};
    for (int k = 0; k < K_; ++k) {
      float indv = indicator[j * K_ + k];
      if (indv != 0.0f) {
        const float* hp = h_mat + ((size_t)dd * K_ + k) * A_;
#pragma unroll
        for (int a = 0; a < A_; ++a) hs[a] = fmaf(indv, hp[a], hs[a]);
      }
    }
    float hv = 0.0f;
#pragma unroll
    for (int a = 0; a < A_; ++a) hv = fmaf(hs[a], a_mat[j * A_ + a], hv);
    hvec[tid] = hv;
    if (tid < J_) {
      float nzv = 0.0f;
#pragma unroll
      for (int a = 0; a < A_; ++a)
        nzv = fmaf(a_mat[tid * A_ + a], noise[tid * A_ + a], nzv);
      nz[tid] = nzv;
    }
  }
}

// 512 blocks (d:8 x bt:16 x oc:4) x 512 thr (8 waves), 2 blocks/CU.
// Each wave: 2 ogs x BOTH bgs. a-frags stream from global (R9 pipelining
// preserved); x-frags in LDS (14KB one-shot stage) so VGPR stays < 128.
// w1a/wca L2 traffic halved vs R9/R13.
__global__ __launch_bounds__(512, 4) void k1(
    const unsigned short* __restrict__ w1a,
    const unsigned short* __restrict__ xa,
    const unsigned short* __restrict__ wca, float* __restrict__ S1part,
    float* __restrict__ spsum, float* __restrict__ spsq) {
  extern __shared__ __align__(16) char smem[];  // 67584 B (red aliases xf)

  const int id = blockIdx.x;
  const int d = id & 7;  // XCD-pinned
  const int rest = id >> 3;
  const int bt = rest & 15, oc = rest >> 4;  // oc in [0,4)
  const int tid = threadIdx.x;
  const int w = tid >> 6, lane = tid & 63;  // w in [0,8)
  const int l31 = lane & 31, hi = lane >> 5;
  const bool lo_half = (hi == 0);

  // stage x fragments for BOTH bgs (14 frags = 14 KB), linear both sides
#pragma unroll
  for (int c = 0; c < 2; ++c) {
    int f = w * 2 + c;
    if (f < 14) {
      int bgl = f / 7, ks = f - bgl * 7;
      const unsigned short* src =
          xa + (size_t)((d * 32 + bt * 2 + bgl) * 7 + ks) * 512 + lane * 8;
      gload16(src, smem + (size_t)f * 1024);
    }
  }
  __syncthreads();  // xf resident (vmcnt drained by barrier)

  f32x16 acc2a = {}, acc2b = {};
  float lsum = 0.0f, lsq = 0.0f;

  for (int og2 = 0; og2 < 2; ++og2) {
    const int og = oc * 16 + w * 2 + og2;
    const unsigned short* ab =
        w1a + (size_t)((d * 64 + og) * 7) * 512 + lane * 8;
    const unsigned short* wb =
        wca + (size_t)((d * 64 + og) * 2) * 512 + lane * 8;
    bf16x8 wc0 = *(const bf16x8*)(wb);
    bf16x8 wc1 = *(const bf16x8*)(wb + 512);

    // GEMM1: one a[] stream feeds two 32x32 chains (bg0, bg1), K=112
    f32x16 acca = {}, accb = {};
#pragma unroll
    for (int ks = 0; ks < 7; ++ks) {
      bf16x8 a = *(const bf16x8*)(ab + (size_t)ks * 512);
      bf16x8 x0 = *(const bf16x8*)(smem + (size_t)ks * 1024 + lane * 16);
      bf16x8 x1 = *(const bf16x8*)(smem + (size_t)(7 + ks) * 1024 + lane * 16);
      acca = __builtin_amdgcn_mfma_f32_32x32x16_bf16(a, x0, acca, 0, 0, 0);
      accb = __builtin_amdgcn_mfma_f32_32x32x16_bf16(a, x1, accb, 0, 0, 0);
    }

    // epilogue x2: relu + stats + in-register P frags -> GEMM2 (R11-verified)
#pragma unroll
    for (int q = 0; q < 2; ++q) {
      const f32x16& src = q ? accb : acca;
      float v[16];
#pragma unroll
      for (int r = 0; r < 16; ++r) {
        v[r] = fmaxf(src[r], 0.0f);
        lsum += v[r];
        lsq = fmaf(v[r], v[r], lsq);
      }
#pragma unroll
      for (int t = 0; t < 2; ++t) {
        unsigned A0 = cvtpk(v[8 * t + 0], v[8 * t + 1]);
        unsigned A1 = cvtpk(v[8 * t + 2], v[8 * t + 3]);
        unsigned B0 = cvtpk(v[8 * t + 4], v[8 * t + 5]);
        unsigned B1 = cvtpk(v[8 * t + 6], v[8 * t + 7]);
        unsigned sA0 = __shfl_xor(A0, 32);
        unsigned sA1 = __shfl_xor(A1, 32);
        unsigned sB0 = __shfl_xor(B0, 32);
        unsigned sB1 = __shfl_xor(B1, 32);
        bfu f;
        f.u[0] = lo_half ? A0 : sB0;
        f.u[1] = lo_half ? A1 : sB1;
        f.u[2] = lo_half ? sA0 : B0;
        f.u[3] = lo_half ? sA1 : B1;
        if (q == 0)
          acc2a = __builtin_amdgcn_mfma_f32_32x32x16_bf16(t == 0 ? wc0 : wc1,
                                                          f.v, acc2a, 0, 0, 0);
        else
          acc2b = __builtin_amdgcn_mfma_f32_32x32x16_bf16(t == 0 ? wc0 : wc1,
                                                          f.v, acc2b, 0, 0, 0);
      }
    }
  }

  __syncthreads();  // xf reads done -> reuse LDS as reduce buffer
  float* redf = (float*)smem;
  {
#pragma unroll
    for (int r = 0; r < 16; ++r) {
      int j = (r & 3) + 8 * (r >> 2) + 4 * hi;
      redf[(w * 2 + 0) * 1056 + l31 * 33 + j] = acc2a[r];
      redf[(w * 2 + 1) * 1056 + l31 * 33 + j] = acc2b[r];
    }
  }
  __syncthreads();

  // sum 8 waves per bg, write final oc-partial coalesced (512 thr, 2 tiles)
  {
    const int half = tid >> 8;          // bg within tile-pair
    const int row = (tid >> 3) & 31;
    const int j0 = (tid & 7) * 4;
    f32x4 s;
#pragma unroll
    for (int e = 0; e < 4; ++e) {
      float acc_ = 0.0f;
#pragma unroll
      for (int ww = 0; ww < 8; ++ww)
        acc_ += redf[(ww * 2 + half) * 1056 + row * 33 + j0 + e];
      s[e] = acc_;
    }
    const int b = (bt * 2 + half) * 32 + row;
    *(f32x4*)(S1part + (((size_t)oc * 1024 + b) * 8 + d) * 32 + j0) = s;
  }

  // stats: per-wave shuffle reduction
#pragma unroll
  for (int off = 32; off; off >>= 1) {
    lsum += __shfl_down(lsum, off);
    lsq += __shfl_down(lsq, off);
  }
  if (lane == 0) {
    spsum[id * 8 + w] = lsum;
    spsq[id * 8 + w] = lsq;
  }
}

#define W3S 33
#define W4S 99

// 250 blocks x 4 rows; prep = pure arithmetic; preloads vectorized
__global__ __launch_bounds__(256) void kB(
    const float* __restrict__ S1part, const float* __restrict__ spsum,
    const float* __restrict__ spsq, const float* __restrict__ wcp,
    const float* __restrict__ hvec, const float* __restrict__ nz,
    const float* __restrict__ bc, const float* __restrict__ b_mat,
    const float* __restrict__ cutb, const float* __restrict__ W3,
    const float* __restrict__ b3, const float* __restrict__ W4,
    const float* __restrict__ b4, const float* __restrict__ Wo,
    const float* __restrict__ bo, float* __restrict__ out) {
  __shared__ float W3l[98 * W3S];
  __shared__ float W4l[49 * W4S];
  __shared__ float Wol[490];
  __shared__ float b3l[98], b4l[49], bol[10];
  __shared__ float cutl[32], coefl[256], konstl[32], wcs[256];
  __shared__ float psum[8][33], psq[8][33];
  __shared__ float mvals[8], vvals[8];
  __shared__ float sh_gm, sh_inv;
  __shared__ float offs[D_][J_];
  __shared__ float h1[4][32];
  __shared__ float h2[4][100];
  __shared__ float h3[4][52];
  __shared__ float lg[4][10];
  __shared__ float lsel[4];

  const int tid = threadIdx.x;

  for (int idx = tid; idx < 784; idx += 256) {  // W3
    float4 v4 = ((const float4*)W3)[idx];
    int p = idx * 4;
    const float vv[4] = {v4.x, v4.y, v4.z, v4.w};
#pragma unroll
    for (int e = 0; e < 4; ++e) {
      int pp = p + e;
      W3l[(pp >> 5) * W3S + (pp & 31)] = vv[e];
    }
  }
  for (int idx = tid; idx < 2401; idx += 256) {  // W4
    float2 v2 = ((const float2*)W4)[idx];
    int p = idx * 2;
    int o = p / 98, k = p - o * 98;
    W4l[o * W4S + k] = v2.x;
    W4l[o * W4S + k + 1] = v2.y;
  }
  if (tid < 245) {
    float2 v2 = ((const float2*)Wo)[tid];
    Wol[2 * tid] = v2.x;
    Wol[2 * tid + 1] = v2.y;
  }
  if (tid < 49) {
    float2 v2 = ((const float2*)b3)[tid];
    b3l[2 * tid] = v2.x;
    b3l[2 * tid + 1] = v2.y;
    b4l[tid] = b4[tid];
  }
  if (tid < 10) bol[tid] = bo[tid];
  if (tid < 32) cutl[tid] = cutb[tid];

  {
    const float4* p = (const float4*)(wcp + (size_t)tid * 8);
    float4 a = p[0], b = p[1];
    wcs[tid] = a.x + a.y + a.z + a.w + b.x + b.y + b.z + b.w;
  }

  {  // stats: slot = id*8 + w, id = rest*8 + dd, rest in [0,64)
    int dd = tid >> 5, i = tid & 31;
    float s = 0.0f, q = 0.0f;
#pragma unroll
    for (int m = 0; m < 2; ++m) {
      int rest = i + m * 32;
      int base = (rest * 8 + dd) * 8;
#pragma unroll
      for (int ww = 0; ww < 8; ++ww) {
        s += spsum[base + ww];
        q += spsq[base + ww];
      }
    }
    psum[dd][i] = s;
    psq[dd][i] = q;
  }
  __syncthreads();
  if (tid < 8) {
    float s = 0.0f, q = 0.0f;
#pragma unroll
    for (int i = 0; i < 32; ++i) {
      s += psum[tid][i];
      q += psq[tid][i];
    }
    const float inv_cnt = 1.0f / ((float)B_ * (float)NXT_);
    float m = s * inv_cnt;
    mvals[tid] = m;
    vvals[tid] = q * inv_cnt - m * m;
  }
  __syncthreads();
  if (tid == 0) {
    float gm = 0.0f, gv = 0.0f;
    for (int dd = 0; dd < 8; ++dd) {
      gm += mvals[dd];
      gv += vvals[dd];
    }
    gm *= 0.125f;
    gv *= 0.125f;
    sh_gm = gm;
    sh_inv = 1.0f / sqrtf(gv + 1e-6f);
  }
  __syncthreads();
  {
    int dd = tid >> 5, j = tid & 31;
    float c = b_mat[dd * J_ + j] * hvec[tid];
    coefl[tid] = c * sh_inv;
    offs[dd][j] = c * (bc[dd * J_ + j] - sh_gm * wcs[tid] * sh_inv);
  }
  __syncthreads();
  if (tid < J_) {
    float s = nz[tid];
#pragma unroll
    for (int dd = 0; dd < D_; ++dd) s += offs[dd][tid];
    konstl[tid] = s;
  }
  __syncthreads();

  const int row = tid >> 6, lane = tid & 63;
  const int b = blockIdx.x * 4 + row;  // 250*4 = 1000 exactly

  if (lane < 32) {
    float rsum = konstl[lane];
#pragma unroll
    for (int dd = 0; dd < D_; ++dd) {
      float s = 0.0f;
#pragma unroll
      for (int p = 0; p < 4; ++p)
        s += S1part[(((size_t)p * 1024 + b) * 8 + dd) * 32 + lane];
      rsum = fmaf(coefl[dd * J_ + lane], s, rsum);
    }
    h1[row][lane] = fmaxf(rsum + cutl[lane], 0.0f);
  }
  __syncthreads();

  for (int o = lane; o < 98; o += 64) {
    float a = b3l[o];
#pragma unroll
    for (int j = 0; j < 32; ++j) a = fmaf(h1[row][j], W3l[o * W3S + j], a);
    h2[row][o] = fmaxf(a, 0.0f);
  }
  __syncthreads();

  if (lane < 49) {
    float a = b4l[lane];
    for (int k = 0; k < 98; ++k)
      a = fmaf(h2[row][k], W4l[lane * W4S + k], a);
    h3[row][lane] = fmaxf(a, 0.0f);
  }
  __syncthreads();

  if (lane < 10) {
    float a = bol[lane];
#pragma unroll
    for (int k = 0; k < 49; ++k) a = fmaf(h3[row][k], Wol[lane * 49 + k], a);
    lg[row][lane] = a;
  }
  __syncthreads();
  if (lane == 0) {
    float mx = lg[row][0];
    for (int i = 1; i < 10; ++i) mx = fmaxf(mx, lg[row][i]);
    float se = 0.0f;
    for (int i = 0; i < 10; ++i) se += expf(lg[row][i] - mx);
    lsel[row] = mx + logf(se);
  }
  __syncthreads();
  if (lane < 10) out[(size_t)b * 10 + lane] = lg[row][lane] - lsel[row];
}

extern "C" void kernel_launch(void* const* d_in, const int* in_sizes, int n_in,
                              void* d_out, int out_size, void* d_ws,
                              size_t ws_size, hipStream_t stream) {
  const float* x = (const float*)d_in[0];
  const float* W1 = (const float*)d_in[1];
  const float* b1 = (const float*)d_in[2];
  const float* Wc = (const float*)d_in[3];
  const float* bc = (const float*)d_in[4];
  const float* cutb = (const float*)d_in[5];
  const float* bmat = (const float*)d_in[6];
  const float* hmat = (const float*)d_in[7];
  const float* amat = (const float*)d_in[8];
  const float* noise = (const float*)d_in[9];
  const float* W3 = (const float*)d_in[10];
  const float* b3 = (const float*)d_in[11];
  const float* W4 = (const float*)d_in[12];
  const float* b4 = (const float*)d_in[13];
  const float* Wo = (const float*)d_in[14];
  const float* bo = (const float*)d_in[15];
  const float* ind = (const float*)d_in[16];

  float* ws = (float*)d_ws;
  float* S1part = ws;                                     // [0, 1048576)
  unsigned short* w1a = (unsigned short*)(ws + 1048576);  // 917,504 us
  unsigned short* xa = (unsigned short*)(ws + 1966080);   // 458,752 us
  unsigned short* wca = (unsigned short*)(ws + 2424832);  // 524,288 us
  float* spsum = ws + 2686976;                            // 4096
  float* spsq = ws + 2691072;                             // 4096
  float* wcp = ws + 2695168;                              // 2048
  float* hvec = ws + 2697216;                             // 256
  float* nz = ws + 2697472;                               // 32

  kcvt<<<833, 256, 0, stream>>>(x, W1, b1, Wc, hmat, amat, noise, ind, w1a,
                                xa, wca, wcp, hvec, nz);
  k1<<<512, 512, 67584, stream>>>(w1a, xa, wca, S1part, spsum, spsq);
  kB<<<250, 256, 0, stream>>>(S1part, spsum, spsq, wcp, hvec, nz, bc, bmat,
                              cutb, W3, b3, W4, b4, Wo, bo, (float*)d_out);
}

// Round 16
// 37.949 us; speedup vs baseline: 1.3335x; 1.3335x over previous
//
#include <hip/hip_runtime.h>
#include <math.h>

#define B_ 1000
#define D_ 8
#define PRE_ 98
#define NXT_ 2048
#define J_ 32
#define K_ 64
#define A_ 5

typedef __attribute__((ext_vector_type(8))) __bf16 bf16x8;
typedef __attribute__((ext_vector_type(4))) float f32x4;
typedef __attribute__((ext_vector_type(16))) float f32x16;
typedef __attribute__((ext_vector_type(8))) unsigned short us8;

__device__ __forceinline__ unsigned cvtpk(float lo, float hi) {
  unsigned r;
  asm("v_cvt_pk_bf16_f32 %0, %1, %2" : "=v"(r) : "v"(lo), "v"(hi));
  return r;
}

union bfu { unsigned u[4]; bf16x8 v; };

// ws layout (float offsets): R12 layout
//   [0, 1048576)        S1part[oc4][1024 b][8 d][32 j] f32 (4 MB)
//   [1048576, 1966080)  w1a fragments   [1966080, 2424832) xa fragments
//   [2424832, 2686976)  wca fragments
//   [2686976, +4096) spsum  [2691072, +4096) spsq  [2695168, +2048) wcp
//   [2697216, +256) hvec[d*32+j]   [2697472, +32) nz[j]

// 833 blocks: [0,512) W1, [512,768) x, [768,832) Wc(+wcsum), 832 = hvec/nz
__global__ __launch_bounds__(256) void kcvt(
    const float* __restrict__ x, const float* __restrict__ W1,
    const float* __restrict__ b1, const float* __restrict__ Wc,
    const float* __restrict__ h_mat, const float* __restrict__ a_mat,
    const float* __restrict__ noise, const float* __restrict__ indicator,
    unsigned short* __restrict__ w1a, unsigned short* __restrict__ xa,
    unsigned short* __restrict__ wca, float* __restrict__ wcp,
    float* __restrict__ hvec, float* __restrict__ nz) {
  __shared__ float sbuf[32 * 257];
  __shared__ float extra[32];
  __shared__ float ws2[32][9];

  const int bid = blockIdx.x, tid = threadIdx.x;

  if (bid < 512) {  // ---- W1: tile (d, og) = 32 rows x 98 k, contiguous ----
    const int d = bid & 7, og = bid >> 3;
    const float* base = W1 + (size_t)3136 * (d * 64 + og);  // 16B-aligned
    for (int idx = tid; idx < 784; idx += 256) {
      float4 v4 = ((const float4*)base)[idx];
      int p = idx * 4;
      const float vv[4] = {v4.x, v4.y, v4.z, v4.w};
#pragma unroll
      for (int e = 0; e < 4; ++e) {
        int pp = p + e;
        int r = pp / 98, k = pp - r * 98;
        sbuf[r * 99 + k] = vv[e];
      }
    }
    if (tid < 32) extra[tid] = b1[d * NXT_ + og * 32 + tid];
    __syncthreads();
    unsigned short* dst = w1a + (size_t)((d * 64 + og) * 7) * 512;
#pragma unroll
    for (int q = 0; q < 2; ++q) {
      int s = tid + q * 256;
      if (s < 448) {
        int ks = s >> 6, l = s & 63;
        int r = l & 31, k0 = ks * 16 + (l >> 5) * 8;
        const float* row = sbuf + r * 99;
        bfu v;
#pragma unroll
        for (int p = 0; p < 4; ++p) {
          int k = k0 + 2 * p;
          float f0 = (k < 98) ? row[k] : ((k == 98) ? extra[r] : 0.0f);
          float f1 = (k + 1 < 98) ? row[k + 1] : ((k + 1 == 98) ? extra[r] : 0.0f);
          v.u[p] = cvtpk(f0, f1);
        }
        *(bf16x8*)(dst + (size_t)s * 8) = v.v;
      }
    }
  } else if (bid < 768) {  // ---- x: tile (d, bg) = 32 rows x 98 k ----
    const int b2 = bid - 512;
    const int d = b2 & 7, bg = b2 >> 3;
    for (int idx = tid; idx < 1568; idx += 256) {  // 32 rows x 49 float2
      int r = idx / 49, c = idx - r * 49;
      int gb = bg * 32 + r;
      float2 v2 = make_float2(0.0f, 0.0f);
      if (gb < B_)
        v2 = *(const float2*)(x + (size_t)gb * (D_ * PRE_) + d * PRE_ + 2 * c);
      sbuf[r * 99 + 2 * c] = v2.x;
      sbuf[r * 99 + 2 * c + 1] = v2.y;
    }
    __syncthreads();
    unsigned short* dst = xa + (size_t)((d * 32 + bg) * 7) * 512;
#pragma unroll
    for (int q = 0; q < 2; ++q) {
      int s = tid + q * 256;
      if (s < 448) {
        int ks = s >> 6, l = s & 63;
        int r = l & 31, k0 = ks * 16 + (l >> 5) * 8;
        bool valid = (bg * 32 + r) < B_;
        const float* row = sbuf + r * 99;
        bfu v;
#pragma unroll
        for (int p = 0; p < 4; ++p) {
          int k = k0 + 2 * p;
          float f0 = 0.0f, f1 = 0.0f;
          if (valid) {
            f0 = (k < 98) ? row[k] : ((k == 98) ? 1.0f : 0.0f);
            f1 = (k + 1 < 98) ? row[k + 1] : ((k + 1 == 98) ? 1.0f : 0.0f);
          }
          v.u[p] = cvtpk(f0, f1);
        }
        *(bf16x8*)(dst + (size_t)s * 8) = v.v;
      }
    }
  } else if (bid < 832) {  // ---- Wc: tile (d, oq) = 32 j-rows x 256 o ----
    const int b3 = bid - 768;
    const int d = b3 & 7, oq = b3 >> 3;
    for (int idx = tid; idx < 2048; idx += 256) {  // 32 rows x 64 float4
      int j = idx >> 6, c = idx & 63;
      float4 v4 = *(const float4*)(Wc + ((size_t)d * J_ + j) * NXT_ +
                                   oq * 256 + 4 * c);
      float* p = sbuf + j * 257 + 4 * c;
      p[0] = v4.x;
      p[1] = v4.y;
      p[2] = v4.z;
      p[3] = v4.w;
    }
    __syncthreads();
    unsigned short* dst = wca + (size_t)((d * 64 + oq * 8) * 2) * 512;
#pragma unroll
    for (int q = 0; q < 4; ++q) {
      int s = tid + q * 256;
      int ogl = s >> 7, t2 = (s >> 6) & 1, l = s & 63;
      int j = l & 31;
      int ol = ogl * 32 + t2 * 16 + (l >> 5) * 8;
      const float* row = sbuf + j * 257 + ol;
      bfu v;
#pragma unroll
      for (int p = 0; p < 4; ++p) v.u[p] = cvtpk(row[2 * p], row[2 * p + 1]);
      *(bf16x8*)(dst + (size_t)s * 8) = v.v;
    }
    {
      int j = tid >> 3, seg = tid & 7;
      const float* row = sbuf + j * 257 + seg * 32;
      float sacc = 0.0f;
#pragma unroll
      for (int i = 0; i < 32; ++i) sacc += row[i];
      ws2[j][seg] = sacc;
    }
    __syncthreads();
    if (tid < 32) {
      float t = 0.0f;
#pragma unroll
      for (int g = 0; g < 8; ++g) t += ws2[tid][g];
      wcp[((size_t)d * 32 + tid) * 8 + oq] = t;
    }
  } else {  // ---- hvec/nz: channel prep hoisted out of kB ----
    int dd = tid >> 5, j = tid & 31;
    float hs[A_] = {0, 0, 0, 0, 0};
    for (int k = 0; k < K_; ++k) {
      float indv = indicator[j * K_ + k];
      if (indv != 0.0f) {
        const float* hp = h_mat + ((size_t)dd * K_ + k) * A_;
#pragma unroll
        for (int a = 0; a < A_; ++a) hs[a] = fmaf(indv, hp[a], hs[a]);
      }
    }
    float hv = 0.0f;
#pragma unroll
    for (int a = 0; a < A_; ++a) hv = fmaf(hs[a], a_mat[j * A_ + a], hv);
    hvec[tid] = hv;
    if (tid < J_) {
      float nzv = 0.0f;
#pragma unroll
      for (int a = 0; a < A_; ++a)
        nzv = fmaf(a_mat[tid * A_ + a], noise[tid * A_ + a], nzv);
      nz[tid] = nzv;
    }
  }
}

// R9-exact k1 (measured ~8us incl gap): 1024 blocks (d:8 x bg:32 x oc:4)
__global__ __launch_bounds__(256, 4) void k1(
    const unsigned short* __restrict__ w1a,
    const unsigned short* __restrict__ xa,
    const unsigned short* __restrict__ wca, float* __restrict__ S1part,
    float* __restrict__ spsum, float* __restrict__ spsq) {
  __shared__ float red[4][32 * 33];

  const int id = blockIdx.x;
  const int d = id & 7;
  const int r2 = id >> 3;
  const int bg = r2 & 31, oc = r2 >> 5;
  const int tid = threadIdx.x;
  const int w = tid >> 6, lane = tid & 63;
  const int l31 = lane & 31, hi = lane >> 5;
  const bool lo_half = (hi == 0);

  bf16x8 xf[7];
  {
    const unsigned short* xb =
        xa + (size_t)((d * 32 + bg) * 7) * 512 + lane * 8;
#pragma unroll
    for (int ks = 0; ks < 7; ++ks) xf[ks] = *(const bf16x8*)(xb + ks * 512);
  }

  f32x16 acc2 = {};
  float lsum = 0.0f, lsq = 0.0f;

#pragma unroll 2
  for (int i = 0; i < 4; ++i) {
    const int og = oc * 16 + w * 4 + i;
    const unsigned short* ab =
        w1a + (size_t)((d * 64 + og) * 7) * 512 + lane * 8;
    const unsigned short* wb =
        wca + (size_t)((d * 64 + og) * 2) * 512 + lane * 8;
    bf16x8 wc0 = *(const bf16x8*)(wb);
    bf16x8 wc1 = *(const bf16x8*)(wb + 512);

    f32x16 acc = {};
#pragma unroll
    for (int ks = 0; ks < 7; ++ks) {
      bf16x8 a = *(const bf16x8*)(ab + ks * 512);
      acc = __builtin_amdgcn_mfma_f32_32x32x16_bf16(a, xf[ks], acc, 0, 0, 0);
    }

    float v[16];
#pragma unroll
    for (int r = 0; r < 16; ++r) {
      v[r] = fmaxf(acc[r], 0.0f);
      lsum += v[r];
      lsq = fmaf(v[r], v[r], lsq);
    }
#pragma unroll
    for (int t = 0; t < 2; ++t) {
      unsigned A0 = cvtpk(v[8 * t + 0], v[8 * t + 1]);
      unsigned A1 = cvtpk(v[8 * t + 2], v[8 * t + 3]);
      unsigned B0 = cvtpk(v[8 * t + 4], v[8 * t + 5]);
      unsigned B1 = cvtpk(v[8 * t + 6], v[8 * t + 7]);
      unsigned sA0 = __shfl_xor(A0, 32);
      unsigned sA1 = __shfl_xor(A1, 32);
      unsigned sB0 = __shfl_xor(B0, 32);
      unsigned sB1 = __shfl_xor(B1, 32);
      bfu f;
      f.u[0] = lo_half ? A0 : sB0;
      f.u[1] = lo_half ? A1 : sB1;
      f.u[2] = lo_half ? sA0 : B0;
      f.u[3] = lo_half ? sA1 : B1;
      acc2 = __builtin_amdgcn_mfma_f32_32x32x16_bf16(t == 0 ? wc0 : wc1, f.v,
                                                     acc2, 0, 0, 0);
    }
  }

  {
    float* tw = red[w];
#pragma unroll
    for (int r = 0; r < 16; ++r) {
      int j = (r & 3) + 8 * (r >> 2) + 4 * hi;
      tw[l31 * 33 + j] = acc2[r];
    }
  }
  __syncthreads();

  {
    const int row = tid >> 3, j0 = (tid & 7) * 4;
    f32x4 s;
#pragma unroll
    for (int e = 0; e < 4; ++e) {
      float acc_ = 0.0f;
#pragma unroll
      for (int ww = 0; ww < 4; ++ww) acc_ += red[ww][row * 33 + j0 + e];
      s[e] = acc_;
    }
    const int b = bg * 32 + row;
    *(f32x4*)(S1part + (((size_t)oc * 1024 + b) * 8 + d) * 32 + j0) = s;
  }

#pragma unroll
  for (int off = 32; off; off >>= 1) {
    lsum += __shfl_down(lsum, off);
    lsq += __shfl_down(lsq, off);
  }
  if (lane == 0) {
    spsum[id * 4 + w] = lsum;
    spsq[id * 4 + w] = lsq;
  }
}

#define W3S 33
#define W4S 99

// 250 blocks x 4 rows; prep = pure arithmetic; preloads vectorized
__global__ __launch_bounds__(256) void kB(
    const float* __restrict__ S1part, const float* __restrict__ spsum,
    const float* __restrict__ spsq, const float* __restrict__ wcp,
    const float* __restrict__ hvec, const float* __restrict__ nz,
    const float* __restrict__ bc, const float* __restrict__ b_mat,
    const float* __restrict__ cutb, const float* __restrict__ W3,
    const float* __restrict__ b3, const float* __restrict__ W4,
    const float* __restrict__ b4, const float* __restrict__ Wo,
    const float* __restrict__ bo, float* __restrict__ out) {
  __shared__ float W3l[98 * W3S];
  __shared__ float W4l[49 * W4S];
  __shared__ float Wol[490];
  __shared__ float b3l[98], b4l[49], bol[10];
  __shared__ float cutl[32], coefl[256], konstl[32], wcs[256];
  __shared__ float psum[8][33], psq[8][33];
  __shared__ float mvals[8], vvals[8];
  __shared__ float sh_gm, sh_inv;
  __shared__ float offs[D_][J_];
  __shared__ float h1[4][32];
  __shared__ float h2[4][100];
  __shared__ float h3[4][52];
  __shared__ float lg[4][10];
  __shared__ float lsel[4];

  const int tid = threadIdx.x;

  for (int idx = tid; idx < 784; idx += 256) {  // W3: 3136 f = 784 f4
    float4 v4 = ((const float4*)W3)[idx];
    int p = idx * 4;
    const float vv[4] = {v4.x, v4.y, v4.z, v4.w};
#pragma unroll
    for (int e = 0; e < 4; ++e) {
      int pp = p + e;
      W3l[(pp >> 5) * W3S + (pp & 31)] = vv[e];
    }
  }
  for (int idx = tid; idx < 2401; idx += 256) {  // W4: 4802 f = 2401 f2
    float2 v2 = ((const float2*)W4)[idx];
    int p = idx * 2;
    int o = p / 98, k = p - o * 98;  // k even, pair never straddles rows
    W4l[o * W4S + k] = v2.x;
    W4l[o * W4S + k + 1] = v2.y;
  }
  if (tid < 245) {  // Wo: 490 f = 245 f2, flat copy
    float2 v2 = ((const float2*)Wo)[tid];
    Wol[2 * tid] = v2.x;
    Wol[2 * tid + 1] = v2.y;
  }
  if (tid < 49) {
    float2 v2 = ((const float2*)b3)[tid];
    b3l[2 * tid] = v2.x;
    b3l[2 * tid + 1] = v2.y;
    b4l[tid] = b4[tid];
  }
  if (tid < 10) bol[tid] = bo[tid];
  if (tid < 32) cutl[tid] = cutb[tid];

  {
    const float4* p = (const float4*)(wcp + (size_t)tid * 8);
    float4 a = p[0], b = p[1];
    wcs[tid] = a.x + a.y + a.z + a.w + b.x + b.y + b.z + b.w;
  }

  {
    int dd = tid >> 5, i = tid & 31;
    float s = 0.0f, q = 0.0f;
#pragma unroll
    for (int m = 0; m < 4; ++m) {
      int k = i + m * 32;
      int base = (k * 8 + dd) * 4;
#pragma unroll
      for (int ww = 0; ww < 4; ++ww) {
        s += spsum[base + ww];
        q += spsq[base + ww];
      }
    }
    psum[dd][i] = s;
    psq[dd][i] = q;
  }
  __syncthreads();
  if (tid < 8) {
    float s = 0.0f, q = 0.0f;
#pragma unroll
    for (int i = 0; i < 32; ++i) {
      s += psum[tid][i];
      q += psq[tid][i];
    }
    const float inv_cnt = 1.0f / ((float)B_ * (float)NXT_);
    float m = s * inv_cnt;
    mvals[tid] = m;
    vvals[tid] = q * inv_cnt - m * m;
  }
  __syncthreads();
  if (tid == 0) {
    float gm = 0.0f, gv = 0.0f;
    for (int dd = 0; dd < 8; ++dd) {
      gm += mvals[dd];
      gv += vvals[dd];
    }
    gm *= 0.125f;
    gv *= 0.125f;
    sh_gm = gm;
    sh_inv = 1.0f / sqrtf(gv + 1e-6f);
  }
  __syncthreads();
  {
    int dd = tid >> 5, j = tid & 31;
    float c = b_mat[dd * J_ + j] * hvec[tid];
    coefl[tid] = c * sh_inv;
    offs[dd][j] = c * (bc[dd * J_ + j] - sh_gm * wcs[tid] * sh_inv);
  }
  __syncthreads();
  if (tid < J_) {
    float s = nz[tid];
#pragma unroll
    for (int dd = 0; dd < D_; ++dd) s += offs[dd][tid];
    konstl[tid] = s;
  }
  __syncthreads();

  const int row = tid >> 6, lane = tid & 63;
  const int b = blockIdx.x * 4 + row;  // 250*4 = 1000 exactly

  if (lane < 32) {
    float rsum = konstl[lane];
#pragma unroll
    for (int dd = 0; dd < D_; ++dd) {
      float s = 0.0f;
#pragma unroll
      for (int p = 0; p < 4; ++p)
        s += S1part[(((size_t)p * 1024 + b) * 8 + dd) * 32 + lane];
      rsum = fmaf(coefl[dd * J_ + lane], s, rsum);
    }
    h1[row][lane] = fmaxf(rsum + cutl[lane], 0.0f);
  }
  __syncthreads();

  for (int o = lane; o < 98; o += 64) {
    float a = b3l[o];
#pragma unroll
    for (int j = 0; j < 32; ++j) a = fmaf(h1[row][j], W3l[o * W3S + j], a);
    h2[row][o] = fmaxf(a, 0.0f);
  }
  __syncthreads();

  if (lane < 49) {
    float a = b4l[lane];
    for (int k = 0; k < 98; ++k)
      a = fmaf(h2[row][k], W4l[lane * W4S + k], a);
    h3[row][lane] = fmaxf(a, 0.0f);
  }
  __syncthreads();

  if (lane < 10) {
    float a = bol[lane];
#pragma unroll
    for (int k = 0; k < 49; ++k) a = fmaf(h3[row][k], Wol[lane * 49 + k], a);
    lg[row][lane] = a;
  }
  __syncthreads();
  if (lane == 0) {
    float mx = lg[row][0];
    for (int i = 1; i < 10; ++i) mx = fmaxf(mx, lg[row][i]);
    float se = 0.0f;
    for (int i = 0; i < 10; ++i) se += expf(lg[row][i] - mx);
    lsel[row] = mx + logf(se);
  }
  __syncthreads();
  if (lane < 10) out[(size_t)b * 10 + lane] = lg[row][lane] - lsel[row];
}

extern "C" void kernel_launch(void* const* d_in, const int* in_sizes, int n_in,
                              void* d_out, int out_size, void* d_ws,
                              size_t ws_size, hipStream_t stream) {
  const float* x = (const float*)d_in[0];
  const float* W1 = (const float*)d_in[1];
  const float* b1 = (const float*)d_in[2];
  const float* Wc = (const float*)d_in[3];
  const float* bc = (const float*)d_in[4];
  const float* cutb = (const float*)d_in[5];
  const float* bmat = (const float*)d_in[6];
  const float* hmat = (const float*)d_in[7];
  const float* amat = (const float*)d_in[8];
  const float* noise = (const float*)d_in[9];
  const float* W3 = (const float*)d_in[10];
  const float* b3 = (const float*)d_in[11];
  const float* W4 = (const float*)d_in[12];
  const float* b4 = (const float*)d_in[13];
  const float* Wo = (const float*)d_in[14];
  const float* bo = (const float*)d_in[15];
  const float* ind = (const float*)d_in[16];

  float* ws = (float*)d_ws;
  float* S1part = ws;                                     // [0, 1048576)
  unsigned short* w1a = (unsigned short*)(ws + 1048576);  // 917,504 us
  unsigned short* xa = (unsigned short*)(ws + 1966080);   // 458,752 us
  unsigned short* wca = (unsigned short*)(ws + 2424832);  // 524,288 us
  float* spsum = ws + 2686976;                            // 4096
  float* spsq = ws + 2691072;                             // 4096
  float* wcp = ws + 2695168;                              // 2048
  float* hvec = ws + 2697216;                             // 256
  float* nz = ws + 2697472;                               // 32

  kcvt<<<833, 256, 0, stream>>>(x, W1, b1, Wc, hmat, amat, noise, ind, w1a,
                                xa, wca, wcp, hvec, nz);
  k1<<<1024, 256, 0, stream>>>(w1a, xa, wca, S1part, spsum, spsq);
  kB<<<250, 256, 0, stream>>>(S1part, spsum, spsq, wcp, hvec, nz, bc, bmat,
                              cutb, W3, b3, W4, b4, Wo, bo, (float*)d_out);
}